// Round 3
// baseline (270.201 us; speedup 1.0000x reference)
//
#include <hip/hip_runtime.h>
#include <hip/hip_bf16.h>
#include <math.h>

#define S_LEN 4096
#define EMB   1024
#define NHEAD 16
#define HDIM  64

typedef __attribute__((ext_vector_type(8))) _Float16 half8;
typedef __attribute__((ext_vector_type(4))) _Float16 half4;
typedef __attribute__((ext_vector_type(2))) _Float16 half2_t;
typedef __attribute__((ext_vector_type(4))) float float4_t;
typedef __attribute__((ext_vector_type(4))) int int4_t;

#define GLOBAL_AS(p) ((const __attribute__((address_space(1))) void*)(p))
#define LDS_AS(p)    ((__attribute__((address_space(3))) void*)(p))

#define LOG2E 1.4426950408889634f

// ---------------------------------------------------------------------------
// fused prep: blocks [0,4096) convert x fp32->fp16; [4096,4864) transpose
// Wqkv [1024,3072] -> WTh [3072,1024]; [4864,5120) transpose Wp -> WpT.
// ---------------------------------------------------------------------------
__global__ __launch_bounds__(256) void prep(
    const float* __restrict__ x, const float* __restrict__ Wqkv,
    const float* __restrict__ Wp,
    _Float16* __restrict__ xh, _Float16* __restrict__ WTh,
    _Float16* __restrict__ WpT)
{
    const int bid = blockIdx.x;
    if (bid < 4096) {
        const int i = bid * 256 + threadIdx.x;
        const float4_t v = ((const float4_t*)x)[i];
        half4 hh;
#pragma unroll
        for (int j = 0; j < 4; ++j) hh[j] = (_Float16)v[j];
        ((half4*)xh)[i] = hh;
        return;
    }
    __shared__ float t[64][65];
    const float* in;
    _Float16* out;
    int R, C, bx, by;
    if (bid < 4096 + 768) {
        const int idx = bid - 4096;
        bx = idx % 48; by = idx / 48;
        in = Wqkv; out = WTh; R = 1024; C = 3072;
    } else {
        const int idx = bid - 4864;
        bx = idx & 15; by = idx >> 4;
        in = Wp; out = WpT; R = 1024; C = 1024;
    }
    const int r0 = by * 64, c0 = bx * 64;
    for (int i = threadIdx.x; i < 64 * 64; i += 256) {
        int r = i >> 6, c = i & 63;
        t[r][c] = in[(size_t)(r0 + r) * C + c0 + c];
    }
    __syncthreads();
    for (int i = threadIdx.x; i < 64 * 64; i += 256) {
        int c = i >> 6, r = i & 63;
        out[(size_t)(c0 + c) * R + r0 + r] = (_Float16)t[r][c];
    }
}

// ---------------------------------------------------------------------------
// QKV GEMM, plain fp16, m97 structure: 128x128 tile, BK=32, global_load_lds.
// Epilogue: cols<1024 -> q plane; 1024..2047 -> k plane SCALED by log2(e);
// cols>=2048 -> fp16 V^T [1024,4096], packed half4 along s.
// ---------------------------------------------------------------------------
__global__ __launch_bounds__(256) void gemm_qkv(
    const _Float16* __restrict__ Ag, const _Float16* __restrict__ Bg,
    const float* __restrict__ bias,
    _Float16* __restrict__ qk, _Float16* __restrict__ vt, int K)
{
    constexpr int BK = 32;
    __shared__ _Float16 Ah[128 * BK];
    __shared__ _Float16 Bh[128 * BK];

    const int tid = threadIdx.x;
    const int wave = tid >> 6, lane = tid & 63;
    const int l16 = lane & 15, quad = lane >> 4;
    const int wr = wave >> 1, wc = wave & 1;
    const int row0 = blockIdx.y * 128, col0 = blockIdx.x * 128;
    const int lrow = lane >> 2, lc8 = (lane & 3) * 8;

    float4_t acc[4][4];
#pragma unroll
    for (int i = 0; i < 4; ++i)
#pragma unroll
        for (int j = 0; j < 4; ++j) acc[i][j] = (float4_t){0.f, 0.f, 0.f, 0.f};

    for (int k0 = 0; k0 < K; k0 += BK) {
        __syncthreads();
#pragma unroll
        for (int i = 0; i < 2; ++i) {
            const int ar = i * 64 + wave * 16;
            __builtin_amdgcn_global_load_lds(
                GLOBAL_AS(Ag + (size_t)(row0 + ar + lrow) * K + k0 + lc8),
                LDS_AS(&Ah[ar * BK]), 16, 0, 0);
            __builtin_amdgcn_global_load_lds(
                GLOBAL_AS(Bg + (size_t)(col0 + ar + lrow) * K + k0 + lc8),
                LDS_AS(&Bh[ar * BK]), 16, 0, 0);
        }
        __syncthreads();

        half8 af[4], bfr[4];
#pragma unroll
        for (int t = 0; t < 4; ++t) {
            af[t]  = *(const half8*)&Ah[(wr * 64 + t * 16 + l16) * BK + quad * 8];
            bfr[t] = *(const half8*)&Bh[(wc * 64 + t * 16 + l16) * BK + quad * 8];
        }
#pragma unroll
        for (int i = 0; i < 4; ++i)
#pragma unroll
            for (int j = 0; j < 4; ++j)
                acc[i][j] = __builtin_amdgcn_mfma_f32_16x16x32_f16(af[i], bfr[j], acc[i][j], 0, 0, 0);
    }

#pragma unroll
    for (int i = 0; i < 4; ++i) {
#pragma unroll
        for (int j = 0; j < 4; ++j) {
            const int colb = col0 + wc * 64 + j * 16 + l16;
            const float bv = bias[colb];
            const int rowb = row0 + wr * 64 + i * 16 + quad * 4;
            if (colb < 2048) {
                const float sc = (colb >= 1024) ? LOG2E : 1.0f;
#pragma unroll
                for (int r = 0; r < 4; ++r)
                    qk[(size_t)(rowb + r) * 2048 + colb] =
                        (_Float16)((acc[i][j][r] + bv) * sc);
            } else {
                half4 w;
#pragma unroll
                for (int r = 0; r < 4; ++r) w[r] = (_Float16)(acc[i][j][r] + bv);
                *(half4*)&vt[(size_t)(colb - 2048) * 4096 + rowb] = w;
            }
        }
    }
}

// ---------------------------------------------------------------------------
// Out-projection GEMM, fp16, 128(M)x64(N) tile -> 512 blocks (2/CU; was 256
// = 1/CU latency-bound). 4 waves: wave owns 32 M-rows x full 64 N.
// ---------------------------------------------------------------------------
__global__ __launch_bounds__(256) void gemm_out(
    const _Float16* __restrict__ Ag, const _Float16* __restrict__ Bg,
    const float* __restrict__ bias, float* __restrict__ C, int N, int K)
{
    constexpr int BK = 32;
    __shared__ _Float16 Ah[128 * BK];
    __shared__ _Float16 Bh[64 * BK];

    const int tid = threadIdx.x;
    const int wave = tid >> 6, lane = tid & 63;
    const int l16 = lane & 15, quad = lane >> 4;
    const int row0 = blockIdx.y * 128, col0 = blockIdx.x * 64;
    const int lrow = lane >> 2, lc8 = (lane & 3) * 8;

    float4_t acc[2][4];
#pragma unroll
    for (int i = 0; i < 2; ++i)
#pragma unroll
        for (int j = 0; j < 4; ++j) acc[i][j] = (float4_t){0.f, 0.f, 0.f, 0.f};

    for (int k0 = 0; k0 < K; k0 += BK) {
        __syncthreads();
#pragma unroll
        for (int i = 0; i < 2; ++i) {
            const int ar = i * 64 + wave * 16;
            __builtin_amdgcn_global_load_lds(
                GLOBAL_AS(Ag + (size_t)(row0 + ar + lrow) * K + k0 + lc8),
                LDS_AS(&Ah[ar * BK]), 16, 0, 0);
        }
        {
            const int br = wave * 16;
            __builtin_amdgcn_global_load_lds(
                GLOBAL_AS(Bg + (size_t)(col0 + br + lrow) * K + k0 + lc8),
                LDS_AS(&Bh[br * BK]), 16, 0, 0);
        }
        __syncthreads();

        half8 af[2], bfr[4];
#pragma unroll
        for (int t = 0; t < 2; ++t)
            af[t] = *(const half8*)&Ah[(wave * 32 + t * 16 + l16) * BK + quad * 8];
#pragma unroll
        for (int t = 0; t < 4; ++t)
            bfr[t] = *(const half8*)&Bh[(t * 16 + l16) * BK + quad * 8];
#pragma unroll
        for (int i = 0; i < 2; ++i)
#pragma unroll
            for (int j = 0; j < 4; ++j)
                acc[i][j] = __builtin_amdgcn_mfma_f32_16x16x32_f16(af[i], bfr[j], acc[i][j], 0, 0, 0);
    }

#pragma unroll
    for (int i = 0; i < 2; ++i) {
#pragma unroll
        for (int j = 0; j < 4; ++j) {
            const int colb = col0 + j * 16 + l16;
            const float bv = bias[colb];
#pragma unroll
            for (int r = 0; r < 4; ++r) {
                const int row = row0 + wave * 32 + i * 16 + quad * 4 + r;
                C[(size_t)row * N + colb] = acc[i][j][r] + bv;
            }
        }
    }
}

// ---------------------------------------------------------------------------
// MFMA causal flash attention — Pb-ELIMINATION round:
// Round-2 post-mortem: ~67% of SIMD cycles issue nothing; LDS pipe carries
// ~96 KB per block-iter (DMA 16K + 4x16K frag reads + 16K Pb) and occupancy
// is LDS-capped at 3 blocks/CU (measured avg ~2). This round:
// (1) Pb LDS round-trip REPLACED by in-register cross-quad exchange:
//     8 cvt_pkrtz packs + 16 ds_bpermute + 8 cndmask. The P-transpose only
//     moves data between the 4 quads of the same l16 group:
//       pb0 word m (keys 8d+2m..+1) = w[d>>1][m&1] from lane
//       l16 + 16*(m>>1) + 32*(d&1); pb1 same with w[2+(d>>1)].
//     -> LDS drops to exactly 32 KB -> 5 blocks/CU = 20 waves/CU cap, and
//     the ds_write->ds_read latency leaves the per-iter critical path.
// (2) defer-max (T13): skip the 16-mul O-rescale unless the row max grows
//     by >8 (log2 domain); alpha = exp2(m_r-mnew) is exactly 1.0 when
//     deferred (no selects needed). p <= 2^8, f32 l/o absorb it.
// (3) l-reduction deferred to epilogue: per-lane partial l_r (alpha chain is
//     row-uniform), 2 shuffles once instead of every iter.
// Structure otherwise = round 2: 1024 blocks x 4 waves, heavy-first LPT,
// head h = (bid&7)*2+((bid>>3)&1) XCD-pinned, 64x64 K/V tiles DMA-staged
// into double-buffered XOR-swizzled LDS, one __syncthreads per k-iter,
// S^T = K Q^T in log2 domain.
// ---------------------------------------------------------------------------
__global__ __launch_bounds__(256, 5) void flash_attn_f16(
    const _Float16* __restrict__ qk, const _Float16* __restrict__ v_t,
    _Float16* __restrict__ resh)
{
    __shared__ __align__(16) _Float16 KsT[2][64 * 64];   // [buf][slot*8]
    __shared__ __align__(16) _Float16 VtT[2][64 * 64];

    const int bid  = blockIdx.x;
    const int h    = (bid & 7) * 2 + ((bid >> 3) & 1);
    const int tile = 63 - (bid >> 4);          // heavy-first (LPT)
    const int wave = threadIdx.x >> 6;         // 0..3
    const int lane = threadIdx.x & 63;
    const int l16  = lane & 15;
    const int quad = lane >> 4;

    // DMA source-address components (lane's LDS slot is wave*128+p*64+lane):
    const int dma_r = wave * 16 + (lane >> 3);             // row  (+ p*8)
    const int dma_c = ((lane & 7) ^ (lane >> 3)) * 8;      // logical col (halfs)

    // bpermute byte-addresses for the P cross-quad exchange
    const int srcA4 = (l16 + ((quad & 1) << 5)) << 2;      // l16 + 32*(d&1)
    const int srcB4 = srcA4 + 64;                          // +16 lanes
    const bool hiT  = quad >= 2;                           // select w[1]/w[3]

    const _Float16* kplane = qk + 1024 + h * HDIM;
    const _Float16* vplane = v_t + (size_t)h * HDIM * 4096;

    const int q0      = tile * 64 + wave * 16;
    const int kb_last = tile * 64;

    // ---- Q fragment (B-operand) -------------------------------------------
    const size_t qoff = (size_t)(q0 + l16) * 2048 + h * HDIM + quad * 8;
    half8 qf0 = *(const half8*)(qk + qoff);
    half8 qf1 = *(const half8*)(qk + qoff + 32);

    float4_t o[4];
#pragma unroll
    for (int c = 0; c < 4; ++c) o[c] = (float4_t){0.f, 0.f, 0.f, 0.f};
    float m_r = -INFINITY, l_r = 0.f;

    // ---- pre-stage tile kb=0 into buf 0 (LDS untouched before this) -------
#pragma unroll
    for (int p = 0; p < 2; ++p) {
        const int r = dma_r + p * 8;
        __builtin_amdgcn_global_load_lds(
            GLOBAL_AS(kplane + (size_t)r * 2048 + dma_c),
            LDS_AS(&KsT[0][(wave * 128 + p * 64) * 8]), 16, 0, 0);
        __builtin_amdgcn_global_load_lds(
            GLOBAL_AS(vplane + (size_t)r * 4096 + dma_c),
            LDS_AS(&VtT[0][(wave * 128 + p * 64) * 8]), 16, 0, 0);
    }

    int ib = 0;
    for (int kb = 0; kb <= kb_last; kb += 64, ib ^= 1) {
        __syncthreads();   // DMA(buf ib) done (vmcnt drain) + readers done

        if (kb < kb_last) {   // async DMA of next tile into the other buf
            const int kn = kb + 64;
#pragma unroll
            for (int p = 0; p < 2; ++p) {
                const int r = dma_r + p * 8;
                __builtin_amdgcn_global_load_lds(
                    GLOBAL_AS(kplane + (size_t)(kn + r) * 2048 + dma_c),
                    LDS_AS(&KsT[ib ^ 1][(wave * 128 + p * 64) * 8]), 16, 0, 0);
                __builtin_amdgcn_global_load_lds(
                    GLOBAL_AS(vplane + (size_t)r * 4096 + kn + dma_c),
                    LDS_AS(&VtT[ib ^ 1][(wave * 128 + p * 64) * 8]), 16, 0, 0);
            }
        }

        // ---- S^T = K Q^T (log2-domain logits) -----------------------------
        float4_t s[4];
#pragma unroll
        for (int t = 0; t < 4; ++t) {
            const int row = t * 16 + l16;
            const int r7 = row & 7;
            half8 a0 = *(const half8*)&KsT[ib][(row * 8 + (quad ^ r7)) * 8];
            half8 a1 = *(const half8*)&KsT[ib][(row * 8 + ((quad + 4) ^ r7)) * 8];
            float4_t a = (float4_t){0.f, 0.f, 0.f, 0.f};
            a = __builtin_amdgcn_mfma_f32_16x16x32_f16(a0, qf0, a, 0, 0, 0);
            a = __builtin_amdgcn_mfma_f32_16x16x32_f16(a1, qf1, a, 0, 0, 0);
            s[t] = a;
        }

        // ---- causal mask (diagonal-straddling tile only) ------------------
        if (kb + 63 > q0) {
            const int qg = q0 + l16;
#pragma unroll
            for (int t = 0; t < 4; ++t)
#pragma unroll
                for (int r = 0; r < 4; ++r) {
                    const int key = kb + t * 16 + quad * 4 + r;
                    if (key > qg) s[t][r] = -INFINITY;
                }
        }

        // ---- online softmax: tree max + 2 shuffles, defer-max (T13) -------
        const float t0m = fmaxf(fmaxf(s[0][0], s[0][1]), fmaxf(s[0][2], s[0][3]));
        const float t1m = fmaxf(fmaxf(s[1][0], s[1][1]), fmaxf(s[1][2], s[1][3]));
        const float t2m = fmaxf(fmaxf(s[2][0], s[2][1]), fmaxf(s[2][2], s[2][3]));
        const float t3m = fmaxf(fmaxf(s[3][0], s[3][1]), fmaxf(s[3][2], s[3][3]));
        float mx = fmaxf(fmaxf(t0m, t1m), fmaxf(t2m, t3m));
        mx = fmaxf(mx, __shfl_xor(mx, 16));
        mx = fmaxf(mx, __shfl_xor(mx, 32));
        const bool  grow  = mx > m_r + 8.0f;
        const float mnew  = grow ? mx : m_r;
        const float alpha = __builtin_amdgcn_exp2f(m_r - mnew);  // ==1 if !grow

        float p[4][4];
        float lsum = 0.f;
#pragma unroll
        for (int t = 0; t < 4; ++t)
#pragma unroll
            for (int r = 0; r < 4; ++r) {
                p[t][r] = __builtin_amdgcn_exp2f(s[t][r] - mnew);
                lsum += p[t][r];
            }
        l_r = l_r * alpha + lsum;       // per-lane partial (alpha row-uniform)
        m_r = mnew;
        if (__any(grow)) {
#pragma unroll
            for (int ct = 0; ct < 4; ++ct)
#pragma unroll
                for (int r = 0; r < 4; ++r) o[ct][r] *= alpha;
        }

        // ---- P exchange: pack + 16 bpermute + select (no LDS) -------------
        int w[4][2];
#pragma unroll
        for (int t = 0; t < 4; ++t) {
            w[t][0] = __builtin_bit_cast(int, __builtin_amdgcn_cvt_pkrtz(p[t][0], p[t][1]));
            w[t][1] = __builtin_bit_cast(int, __builtin_amdgcn_cvt_pkrtz(p[t][2], p[t][3]));
        }
        int4_t v0, v1;
        {
            const int a0 = __builtin_amdgcn_ds_bpermute(srcA4, w[0][0]);
            const int a1 = __builtin_amdgcn_ds_bpermute(srcA4, w[1][0]);
            v0[0] = hiT ? a1 : a0;
            const int b0 = __builtin_amdgcn_ds_bpermute(srcA4, w[0][1]);
            const int b1 = __builtin_amdgcn_ds_bpermute(srcA4, w[1][1]);
            v0[1] = hiT ? b1 : b0;
            const int c0 = __builtin_amdgcn_ds_bpermute(srcB4, w[0][0]);
            const int c1 = __builtin_amdgcn_ds_bpermute(srcB4, w[1][0]);
            v0[2] = hiT ? c1 : c0;
            const int d0 = __builtin_amdgcn_ds_bpermute(srcB4, w[0][1]);
            const int d1 = __builtin_amdgcn_ds_bpermute(srcB4, w[1][1]);
            v0[3] = hiT ? d1 : d0;
            const int e0 = __builtin_amdgcn_ds_bpermute(srcA4, w[2][0]);
            const int e1 = __builtin_amdgcn_ds_bpermute(srcA4, w[3][0]);
            v1[0] = hiT ? e1 : e0;
            const int f0 = __builtin_amdgcn_ds_bpermute(srcA4, w[2][1]);
            const int f1 = __builtin_amdgcn_ds_bpermute(srcA4, w[3][1]);
            v1[1] = hiT ? f1 : f0;
            const int g0 = __builtin_amdgcn_ds_bpermute(srcB4, w[2][0]);
            const int g1 = __builtin_amdgcn_ds_bpermute(srcB4, w[3][0]);
            v1[2] = hiT ? g1 : g0;
            const int h0 = __builtin_amdgcn_ds_bpermute(srcB4, w[2][1]);
            const int h1 = __builtin_amdgcn_ds_bpermute(srcB4, w[3][1]);
            v1[3] = hiT ? h1 : h0;
        }
        const half8 pb0 = __builtin_bit_cast(half8, v0);
        const half8 pb1 = __builtin_bit_cast(half8, v1);

        // ---- O^T += V^T P^T -----------------------------------------------
#pragma unroll
        for (int ct = 0; ct < 4; ++ct) {
            const int row = ct * 16 + l16;
            const int r7 = row & 7;
            half8 va0 = *(const half8*)&VtT[ib][(row * 8 + (quad ^ r7)) * 8];
            half8 va1 = *(const half8*)&VtT[ib][(row * 8 + ((quad + 4) ^ r7)) * 8];
            o[ct] = __builtin_amdgcn_mfma_f32_16x16x32_f16(va0, pb0, o[ct], 0, 0, 0);
            o[ct] = __builtin_amdgcn_mfma_f32_16x16x32_f16(va1, pb1, o[ct], 0, 0, 0);
        }
    } // kb

    // ---- epilogue: reduce l across quads, O^T[d][q]/l -> resh[q][d] -------
    float lr = l_r + __shfl_xor(l_r, 16);
    lr += __shfl_xor(lr, 32);
    const float inv = 1.0f / lr;
#pragma unroll
    for (int ct = 0; ct < 4; ++ct) {
        half4 w;
#pragma unroll
        for (int r = 0; r < 4; ++r) w[r] = (_Float16)(o[ct][r] * inv);
        *(half4*)&resh[(size_t)(q0 + l16) * EMB + h * HDIM + ct * 16 + quad * 4] = w;
    }
}

// ---------------------------------------------------------------------------
// launch
// ---------------------------------------------------------------------------
extern "C" void kernel_launch(void* const* d_in, const int* in_sizes, int n_in,
                              void* d_out, int out_size, void* d_ws, size_t ws_size,
                              hipStream_t stream)
{
    const float* x    = (const float*)d_in[0];
    const float* Wqkv = (const float*)d_in[2];
    const float* bqkv = (const float*)d_in[3];
    const float* Wp   = (const float*)d_in[4];
    const float* bp   = (const float*)d_in[5];
    float* out = (float*)d_out;

    _Float16* xh  = (_Float16*)d_ws;                 // [4096,1024] fp16
    _Float16* WTh = xh + (size_t)4096 * 1024;        // [3072,1024] fp16
    _Float16* qkh = WTh + (size_t)3072 * 1024;       // [4096,2048] fp16
    _Float16* vtg = qkh + (size_t)4096 * 2048;       // V^T [1024,4096] fp16
    _Float16* WpT = vtg + (size_t)1024 * 4096;       // [1024,1024] fp16
    _Float16* resh = xh;            // alias: x fp16 dead after QKV GEMM

    dim3 blk(256);

    prep<<<dim3(5120), blk, 0, stream>>>(x, Wqkv, Wp, xh, WTh, WpT);

    gemm_qkv<<<dim3(3072 / 128, 4096 / 128), blk, 0, stream>>>(
        xh, WTh, bqkv, qkh, vtg, 1024);

    flash_attn_f16<<<dim3(1024), dim3(256), 0, stream>>>(qkh, vtg, resh);

    gemm_out<<<dim3(1024 / 64, 4096 / 128), blk, 0, stream>>>(
        resh, WpT, bp, out, 1024, 1024);
}

// Round 4
// 264.388 us; speedup vs baseline: 1.0220x; 1.0220x over previous
//
#include <hip/hip_runtime.h>
#include <hip/hip_bf16.h>
#include <math.h>

#define S_LEN 4096
#define EMB   1024
#define NHEAD 16
#define HDIM  64

typedef __attribute__((ext_vector_type(8))) _Float16 half8;
typedef __attribute__((ext_vector_type(4))) _Float16 half4;
typedef __attribute__((ext_vector_type(4))) float float4_t;

#define GLOBAL_AS(p) ((const __attribute__((address_space(1))) void*)(p))
#define LDS_AS(p)    ((__attribute__((address_space(3))) void*)(p))

#define LOG2E 1.4426950408889634f

// ---------------------------------------------------------------------------
// fused prep: blocks [0,4096) convert x fp32->fp16; [4096,4864) transpose
// Wqkv [1024,3072] -> WTh [3072,1024]; [4864,5120) transpose Wp -> WpT.
// ---------------------------------------------------------------------------
__global__ __launch_bounds__(256) void prep(
    const float* __restrict__ x, const float* __restrict__ Wqkv,
    const float* __restrict__ Wp,
    _Float16* __restrict__ xh, _Float16* __restrict__ WTh,
    _Float16* __restrict__ WpT)
{
    const int bid = blockIdx.x;
    if (bid < 4096) {
        const int i = bid * 256 + threadIdx.x;
        const float4_t v = ((const float4_t*)x)[i];
        half4 hh;
#pragma unroll
        for (int j = 0; j < 4; ++j) hh[j] = (_Float16)v[j];
        ((half4*)xh)[i] = hh;
        return;
    }
    __shared__ float t[64][65];
    const float* in;
    _Float16* out;
    int R, C, bx, by;
    if (bid < 4096 + 768) {
        const int idx = bid - 4096;
        bx = idx % 48; by = idx / 48;
        in = Wqkv; out = WTh; R = 1024; C = 3072;
    } else {
        const int idx = bid - 4864;
        bx = idx & 15; by = idx >> 4;
        in = Wp; out = WpT; R = 1024; C = 1024;
    }
    const int r0 = by * 64, c0 = bx * 64;
    for (int i = threadIdx.x; i < 64 * 64; i += 256) {
        int r = i >> 6, c = i & 63;
        t[r][c] = in[(size_t)(r0 + r) * C + c0 + c];
    }
    __syncthreads();
    for (int i = threadIdx.x; i < 64 * 64; i += 256) {
        int c = i >> 6, r = i & 63;
        out[(size_t)(c0 + c) * R + r0 + r] = (_Float16)t[r][c];
    }
}

// ---------------------------------------------------------------------------
// QKV GEMM, plain fp16, m97 structure: 128x128 tile, BK=32, global_load_lds.
// Epilogue: cols<1024 -> q plane; 1024..2047 -> k plane SCALED by log2(e);
// cols>=2048 -> fp16 V^T [1024,4096], packed half4 along s.
// ---------------------------------------------------------------------------
__global__ __launch_bounds__(256) void gemm_qkv(
    const _Float16* __restrict__ Ag, const _Float16* __restrict__ Bg,
    const float* __restrict__ bias,
    _Float16* __restrict__ qk, _Float16* __restrict__ vt, int K)
{
    constexpr int BK = 32;
    __shared__ _Float16 Ah[128 * BK];
    __shared__ _Float16 Bh[128 * BK];

    const int tid = threadIdx.x;
    const int wave = tid >> 6, lane = tid & 63;
    const int l16 = lane & 15, quad = lane >> 4;
    const int wr = wave >> 1, wc = wave & 1;
    const int row0 = blockIdx.y * 128, col0 = blockIdx.x * 128;
    const int lrow = lane >> 2, lc8 = (lane & 3) * 8;

    float4_t acc[4][4];
#pragma unroll
    for (int i = 0; i < 4; ++i)
#pragma unroll
        for (int j = 0; j < 4; ++j) acc[i][j] = (float4_t){0.f, 0.f, 0.f, 0.f};

    for (int k0 = 0; k0 < K; k0 += BK) {
        __syncthreads();
#pragma unroll
        for (int i = 0; i < 2; ++i) {
            const int ar = i * 64 + wave * 16;
            __builtin_amdgcn_global_load_lds(
                GLOBAL_AS(Ag + (size_t)(row0 + ar + lrow) * K + k0 + lc8),
                LDS_AS(&Ah[ar * BK]), 16, 0, 0);
            __builtin_amdgcn_global_load_lds(
                GLOBAL_AS(Bg + (size_t)(col0 + ar + lrow) * K + k0 + lc8),
                LDS_AS(&Bh[ar * BK]), 16, 0, 0);
        }
        __syncthreads();

        half8 af[4], bfr[4];
#pragma unroll
        for (int t = 0; t < 4; ++t) {
            af[t]  = *(const half8*)&Ah[(wr * 64 + t * 16 + l16) * BK + quad * 8];
            bfr[t] = *(const half8*)&Bh[(wc * 64 + t * 16 + l16) * BK + quad * 8];
        }
#pragma unroll
        for (int i = 0; i < 4; ++i)
#pragma unroll
            for (int j = 0; j < 4; ++j)
                acc[i][j] = __builtin_amdgcn_mfma_f32_16x16x32_f16(af[i], bfr[j], acc[i][j], 0, 0, 0);
    }

#pragma unroll
    for (int i = 0; i < 4; ++i) {
#pragma unroll
        for (int j = 0; j < 4; ++j) {
            const int colb = col0 + wc * 64 + j * 16 + l16;
            const float bv = bias[colb];
            const int rowb = row0 + wr * 64 + i * 16 + quad * 4;
            if (colb < 2048) {
                const float sc = (colb >= 1024) ? LOG2E : 1.0f;
#pragma unroll
                for (int r = 0; r < 4; ++r)
                    qk[(size_t)(rowb + r) * 2048 + colb] =
                        (_Float16)((acc[i][j][r] + bv) * sc);
            } else {
                half4 w;
#pragma unroll
                for (int r = 0; r < 4; ++r) w[r] = (_Float16)(acc[i][j][r] + bv);
                *(half4*)&vt[(size_t)(colb - 2048) * 4096 + rowb] = w;
            }
        }
    }
}

// ---------------------------------------------------------------------------
// Out-projection GEMM, fp16, 128(M)x64(N) tile -> 512 blocks (2/CU; was 256
// = 1/CU latency-bound). 4 waves: wave owns 32 M-rows x full 64 N.
// ---------------------------------------------------------------------------
__global__ __launch_bounds__(256) void gemm_out(
    const _Float16* __restrict__ Ag, const _Float16* __restrict__ Bg,
    const float* __restrict__ bias, float* __restrict__ C, int N, int K)
{
    constexpr int BK = 32;
    __shared__ _Float16 Ah[128 * BK];
    __shared__ _Float16 Bh[64 * BK];

    const int tid = threadIdx.x;
    const int wave = tid >> 6, lane = tid & 63;
    const int l16 = lane & 15, quad = lane >> 4;
    const int row0 = blockIdx.y * 128, col0 = blockIdx.x * 64;
    const int lrow = lane >> 2, lc8 = (lane & 3) * 8;

    float4_t acc[2][4];
#pragma unroll
    for (int i = 0; i < 2; ++i)
#pragma unroll
        for (int j = 0; j < 4; ++j) acc[i][j] = (float4_t){0.f, 0.f, 0.f, 0.f};

    for (int k0 = 0; k0 < K; k0 += BK) {
        __syncthreads();
#pragma unroll
        for (int i = 0; i < 2; ++i) {
            const int ar = i * 64 + wave * 16;
            __builtin_amdgcn_global_load_lds(
                GLOBAL_AS(Ag + (size_t)(row0 + ar + lrow) * K + k0 + lc8),
                LDS_AS(&Ah[ar * BK]), 16, 0, 0);
        }
        {
            const int br = wave * 16;
            __builtin_amdgcn_global_load_lds(
                GLOBAL_AS(Bg + (size_t)(col0 + br + lrow) * K + k0 + lc8),
                LDS_AS(&Bh[br * BK]), 16, 0, 0);
        }
        __syncthreads();

        half8 af[2], bfr[4];
#pragma unroll
        for (int t = 0; t < 2; ++t)
            af[t] = *(const half8*)&Ah[(wave * 32 + t * 16 + l16) * BK + quad * 8];
#pragma unroll
        for (int t = 0; t < 4; ++t)
            bfr[t] = *(const half8*)&Bh[(t * 16 + l16) * BK + quad * 8];
#pragma unroll
        for (int i = 0; i < 2; ++i)
#pragma unroll
            for (int j = 0; j < 4; ++j)
                acc[i][j] = __builtin_amdgcn_mfma_f32_16x16x32_f16(af[i], bfr[j], acc[i][j], 0, 0, 0);
    }

#pragma unroll
    for (int i = 0; i < 2; ++i) {
#pragma unroll
        for (int j = 0; j < 4; ++j) {
            const int colb = col0 + j * 16 + l16;
            const float bv = bias[colb];
#pragma unroll
            for (int r = 0; r < 4; ++r) {
                const int row = row0 + wave * 32 + i * 16 + quad * 4 + r;
                C[(size_t)row * N + colb] = acc[i][j][r] + bv;
            }
        }
    }
}

// ---------------------------------------------------------------------------
// MFMA causal flash attention — 8-WAVE BLOCK round.
// Round-3 post-mortem: bpermute P-exchange REGRESSED (4.26M bank conflicts,
// VALUBusy 52->38) -> reverted to the round-2 Pb LDS round-trip (0
// conflicts). Round-2 analysis also showed occupancy was GRID-capped (1024
// blocks = 4 blocks/CU avg), and per-iter barrier+DMA overhead dominated.
// This round: 512 blocks x 512 threads (8 waves), q-tile = 128 rows, each
// wave still owns 16 q-rows vs the SAME shared 64-key K/V tiles:
//  - 2 blocks/CU x 8 waves = 16 waves/CU (4/SIMD): 2x round-2 latency hiding
//    (LDS 51.5 KB/block -> up to 3 blocks fit; grid avg 2).
//  - total block-iters 33280 -> 16896: half the barriers, half the K/V DMA.
//  - waves 0..3 skip the single fully-masked trailing k-tile (wave-uniform).
// Kept from round 3: defer-max (T13, skip O-rescale unless row max grows >8
// in log2 domain) and epilogue-deferred l cross-quad reduction.
// Structure otherwise = round 2: heavy-first LPT (tile = 31-(bid>>4)),
// head h = (bid&7)*2+((bid>>3)&1) XCD-pinned, 64x64 K/V tiles DMA-staged
// into double-buffered XOR-swizzled LDS (source-permuted, dest linear):
//   physical slot(row, col8) = row*8 + (col8 ^ (row & 7)), 16 B per slot.
// ONE __syncthreads per k-iter; S^T = K Q^T in log2 domain; P via per-wave
// Pb (stride 76: ~2-way banks), 4x b64 write + 2x b128 read.
// ---------------------------------------------------------------------------
__global__ __launch_bounds__(512, 4) void flash_attn_f16(
    const _Float16* __restrict__ qk, const _Float16* __restrict__ v_t,
    _Float16* __restrict__ resh)
{
    __shared__ __align__(16) _Float16 KsT[2][64 * 64];   // [buf][slot*8]
    __shared__ __align__(16) _Float16 VtT[2][64 * 64];
    __shared__ __align__(16) _Float16 Pb[8][16][76];     // per-wave P [q][key]

    const int bid  = blockIdx.x;
    const int h    = (bid & 7) * 2 + ((bid >> 3) & 1);
    const int tile = 31 - (bid >> 4);          // heavy-first (LPT), 0..31
    const int wave = threadIdx.x >> 6;         // 0..7
    const int lane = threadIdx.x & 63;
    const int l16  = lane & 15;
    const int quad = lane >> 4;

    // DMA source-address components (lane's LDS slot is wave*64+lane; wave w
    // stages rows w*8..w*8+7 of the 64-row tile):
    const int dma_r = wave * 8 + (lane >> 3);              // row
    const int dma_c = ((lane & 7) ^ (lane >> 3)) * 8;      // logical col (halfs)

    const _Float16* kplane = qk + 1024 + h * HDIM;
    const _Float16* vplane = v_t + (size_t)h * HDIM * 4096;

    const int q0      = tile * 128 + wave * 16;
    const int kb_last = tile * 128 + 64;       // last 64-key tile start

    // ---- Q fragment (B-operand) -------------------------------------------
    const size_t qoff = (size_t)(q0 + l16) * 2048 + h * HDIM + quad * 8;
    half8 qf0 = *(const half8*)(qk + qoff);
    half8 qf1 = *(const half8*)(qk + qoff + 32);

    float4_t o[4];
#pragma unroll
    for (int c = 0; c < 4; ++c) o[c] = (float4_t){0.f, 0.f, 0.f, 0.f};
    float m_r = -INFINITY, l_r = 0.f;

    // ---- pre-stage tile kb=0 into buf 0 (LDS untouched before this) -------
    {
        __builtin_amdgcn_global_load_lds(
            GLOBAL_AS(kplane + (size_t)dma_r * 2048 + dma_c),
            LDS_AS(&KsT[0][(wave * 64) * 8]), 16, 0, 0);
        __builtin_amdgcn_global_load_lds(
            GLOBAL_AS(vplane + (size_t)dma_r * 4096 + dma_c),
            LDS_AS(&VtT[0][(wave * 64) * 8]), 16, 0, 0);
    }

    int ib = 0;
    for (int kb = 0; kb <= kb_last; kb += 64, ib ^= 1) {
        __syncthreads();   // DMA(buf ib) done (vmcnt drain) + readers done

        if (kb < kb_last) {   // async DMA of next tile into the other buf
            const int kn = kb + 64;
            __builtin_amdgcn_global_load_lds(
                GLOBAL_AS(kplane + (size_t)(kn + dma_r) * 2048 + dma_c),
                LDS_AS(&KsT[ib ^ 1][(wave * 64) * 8]), 16, 0, 0);
            __builtin_amdgcn_global_load_lds(
                GLOBAL_AS(vplane + (size_t)dma_r * 4096 + kn + dma_c),
                LDS_AS(&VtT[ib ^ 1][(wave * 64) * 8]), 16, 0, 0);
        }

        // waves 0..3: the final k-tile is entirely above the diagonal
        if (kb <= q0 + 15) {
            // ---- S^T = K Q^T (log2-domain logits) -------------------------
            float4_t s[4];
#pragma unroll
            for (int t = 0; t < 4; ++t) {
                const int row = t * 16 + l16;
                const int r7 = row & 7;
                half8 a0 = *(const half8*)&KsT[ib][(row * 8 + (quad ^ r7)) * 8];
                half8 a1 = *(const half8*)&KsT[ib][(row * 8 + ((quad + 4) ^ r7)) * 8];
                float4_t a = (float4_t){0.f, 0.f, 0.f, 0.f};
                a = __builtin_amdgcn_mfma_f32_16x16x32_f16(a0, qf0, a, 0, 0, 0);
                a = __builtin_amdgcn_mfma_f32_16x16x32_f16(a1, qf1, a, 0, 0, 0);
                s[t] = a;
            }

            // ---- causal mask (diagonal-straddling tile only) --------------
            if (kb + 63 > q0) {
                const int qg = q0 + l16;
#pragma unroll
                for (int t = 0; t < 4; ++t)
#pragma unroll
                    for (int r = 0; r < 4; ++r) {
                        const int key = kb + t * 16 + quad * 4 + r;
                        if (key > qg) s[t][r] = -INFINITY;
                    }
            }

            // ---- online softmax: tree max + 2 shuffles, defer-max ---------
            const float t0m = fmaxf(fmaxf(s[0][0], s[0][1]), fmaxf(s[0][2], s[0][3]));
            const float t1m = fmaxf(fmaxf(s[1][0], s[1][1]), fmaxf(s[1][2], s[1][3]));
            const float t2m = fmaxf(fmaxf(s[2][0], s[2][1]), fmaxf(s[2][2], s[2][3]));
            const float t3m = fmaxf(fmaxf(s[3][0], s[3][1]), fmaxf(s[3][2], s[3][3]));
            float mx = fmaxf(fmaxf(t0m, t1m), fmaxf(t2m, t3m));
            mx = fmaxf(mx, __shfl_xor(mx, 16));
            mx = fmaxf(mx, __shfl_xor(mx, 32));
            const bool  grow  = mx > m_r + 8.0f;
            const float mnew  = grow ? mx : m_r;
            const float alpha = __builtin_amdgcn_exp2f(m_r - mnew);  // ==1 if !grow

            float p[4][4];
            float lsum = 0.f;
#pragma unroll
            for (int t = 0; t < 4; ++t)
#pragma unroll
                for (int r = 0; r < 4; ++r) {
                    p[t][r] = __builtin_amdgcn_exp2f(s[t][r] - mnew);
                    lsum += p[t][r];
                }
            l_r = l_r * alpha + lsum;   // per-lane partial (alpha row-uniform)
            m_r = mnew;
            if (__any(grow)) {
#pragma unroll
                for (int ct = 0; ct < 4; ++ct)
#pragma unroll
                    for (int r = 0; r < 4; ++r) o[ct][r] *= alpha;
            }

            // ---- P store (4 keys contiguous) + read-back as B-operand -----
#pragma unroll
            for (int t = 0; t < 4; ++t) {
                half4 w;
#pragma unroll
                for (int r = 0; r < 4; ++r) w[r] = (_Float16)p[t][r];
                *(half4*)&Pb[wave][l16][t * 16 + quad * 4] = w;
            }
            half8 pb0 = *(const half8*)&Pb[wave][l16][quad * 8];
            half8 pb1 = *(const half8*)&Pb[wave][l16][32 + quad * 8];

            // ---- O^T += V^T P^T -------------------------------------------
#pragma unroll
            for (int ct = 0; ct < 4; ++ct) {
                const int row = ct * 16 + l16;
                const int r7 = row & 7;
                half8 va0 = *(const half8*)&VtT[ib][(row * 8 + (quad ^ r7)) * 8];
                half8 va1 = *(const half8*)&VtT[ib][(row * 8 + ((quad + 4) ^ r7)) * 8];
                o[ct] = __builtin_amdgcn_mfma_f32_16x16x32_f16(va0, pb0, o[ct], 0, 0, 0);
                o[ct] = __builtin_amdgcn_mfma_f32_16x16x32_f16(va1, pb1, o[ct], 0, 0, 0);
            }
        } // active
    } // kb

    // ---- epilogue: reduce l across quads, O^T[d][q]/l -> resh[q][d] -------
    float lr = l_r + __shfl_xor(l_r, 16);
    lr += __shfl_xor(lr, 32);
    const float inv = 1.0f / lr;
#pragma unroll
    for (int ct = 0; ct < 4; ++ct) {
        half4 w;
#pragma unroll
        for (int r = 0; r < 4; ++r) w[r] = (_Float16)(o[ct][r] * inv);
        *(half4*)&resh[(size_t)(q0 + l16) * EMB + h * HDIM + ct * 16 + quad * 4] = w;
    }
}

// ---------------------------------------------------------------------------
// launch
// ---------------------------------------------------------------------------
extern "C" void kernel_launch(void* const* d_in, const int* in_sizes, int n_in,
                              void* d_out, int out_size, void* d_ws, size_t ws_size,
                              hipStream_t stream)
{
    const float* x    = (const float*)d_in[0];
    const float* Wqkv = (const float*)d_in[2];
    const float* bqkv = (const float*)d_in[3];
    const float* Wp   = (const float*)d_in[4];
    const float* bp   = (const float*)d_in[5];
    float* out = (float*)d_out;

    _Float16* xh  = (_Float16*)d_ws;                 // [4096,1024] fp16
    _Float16* WTh = xh + (size_t)4096 * 1024;        // [3072,1024] fp16
    _Float16* qkh = WTh + (size_t)3072 * 1024;       // [4096,2048] fp16
    _Float16* vtg = qkh + (size_t)4096 * 2048;       // V^T [1024,4096] fp16
    _Float16* WpT = vtg + (size_t)1024 * 4096;       // [1024,1024] fp16
    _Float16* resh = xh;            // alias: x fp16 dead after QKV GEMM

    dim3 blk(256);

    prep<<<dim3(5120), blk, 0, stream>>>(x, Wqkv, Wp, xh, WTh, WpT);

    gemm_qkv<<<dim3(3072 / 128, 4096 / 128), blk, 0, stream>>>(
        xh, WTh, bqkv, qkh, vtg, 1024);

    flash_attn_f16<<<dim3(512), dim3(512), 0, stream>>>(qkh, vtg, resh);

    gemm_out<<<dim3(1024 / 64, 4096 / 128), blk, 0, stream>>>(
        resh, WpT, bp, out, 1024, 1024);
}

// Round 5
// 263.788 us; speedup vs baseline: 1.0243x; 1.0023x over previous
//
#include <hip/hip_runtime.h>
#include <hip/hip_bf16.h>
#include <math.h>

#define S_LEN 4096
#define EMB   1024
#define NHEAD 16
#define HDIM  64

typedef __attribute__((ext_vector_type(8))) _Float16 half8;
typedef __attribute__((ext_vector_type(4))) _Float16 half4;
typedef __attribute__((ext_vector_type(4))) float float4_t;
typedef __attribute__((ext_vector_type(16))) float float16_t;
typedef __attribute__((ext_vector_type(4))) int int4_t;
typedef __attribute__((ext_vector_type(2))) int int2_t;

#define GLOBAL_AS(p) ((const __attribute__((address_space(1))) void*)(p))
#define LDS_AS(p)    ((__attribute__((address_space(3))) void*)(p))

#define LOG2E 1.4426950408889634f

// ---------------------------------------------------------------------------
// fused prep: blocks [0,4096) convert x fp32->fp16; [4096,4864) transpose
// Wqkv [1024,3072] -> WTh [3072,1024]; [4864,5120) transpose Wp -> WpT.
// ---------------------------------------------------------------------------
__global__ __launch_bounds__(256) void prep(
    const float* __restrict__ x, const float* __restrict__ Wqkv,
    const float* __restrict__ Wp,
    _Float16* __restrict__ xh, _Float16* __restrict__ WTh,
    _Float16* __restrict__ WpT)
{
    const int bid = blockIdx.x;
    if (bid < 4096) {
        const int i = bid * 256 + threadIdx.x;
        const float4_t v = ((const float4_t*)x)[i];
        half4 hh;
#pragma unroll
        for (int j = 0; j < 4; ++j) hh[j] = (_Float16)v[j];
        ((half4*)xh)[i] = hh;
        return;
    }
    __shared__ float t[64][65];
    const float* in;
    _Float16* out;
    int R, C, bx, by;
    if (bid < 4096 + 768) {
        const int idx = bid - 4096;
        bx = idx % 48; by = idx / 48;
        in = Wqkv; out = WTh; R = 1024; C = 3072;
    } else {
        const int idx = bid - 4864;
        bx = idx & 15; by = idx >> 4;
        in = Wp; out = WpT; R = 1024; C = 1024;
    }
    const int r0 = by * 64, c0 = bx * 64;
    for (int i = threadIdx.x; i < 64 * 64; i += 256) {
        int r = i >> 6, c = i & 63;
        t[r][c] = in[(size_t)(r0 + r) * C + c0 + c];
    }
    __syncthreads();
    for (int i = threadIdx.x; i < 64 * 64; i += 256) {
        int c = i >> 6, r = i & 63;
        out[(size_t)(c0 + c) * R + r0 + r] = (_Float16)t[r][c];
    }
}

// ---------------------------------------------------------------------------
// QKV GEMM, plain fp16, m97 structure: 128x128 tile, BK=32, global_load_lds.
// Epilogue: cols<1024 -> q plane; 1024..2047 -> k plane SCALED by log2(e);
// cols>=2048 -> fp16 V^T [1024,4096], packed half4 along s.
// ---------------------------------------------------------------------------
__global__ __launch_bounds__(256) void gemm_qkv(
    const _Float16* __restrict__ Ag, const _Float16* __restrict__ Bg,
    const float* __restrict__ bias,
    _Float16* __restrict__ qk, _Float16* __restrict__ vt, int K)
{
    constexpr int BK = 32;
    __shared__ _Float16 Ah[128 * BK];
    __shared__ _Float16 Bh[128 * BK];

    const int tid = threadIdx.x;
    const int wave = tid >> 6, lane = tid & 63;
    const int l16 = lane & 15, quad = lane >> 4;
    const int wr = wave >> 1, wc = wave & 1;
    const int row0 = blockIdx.y * 128, col0 = blockIdx.x * 128;
    const int lrow = lane >> 2, lc8 = (lane & 3) * 8;

    float4_t acc[4][4];
#pragma unroll
    for (int i = 0; i < 4; ++i)
#pragma unroll
        for (int j = 0; j < 4; ++j) acc[i][j] = (float4_t){0.f, 0.f, 0.f, 0.f};

    for (int k0 = 0; k0 < K; k0 += BK) {
        __syncthreads();
#pragma unroll
        for (int i = 0; i < 2; ++i) {
            const int ar = i * 64 + wave * 16;
            __builtin_amdgcn_global_load_lds(
                GLOBAL_AS(Ag + (size_t)(row0 + ar + lrow) * K + k0 + lc8),
                LDS_AS(&Ah[ar * BK]), 16, 0, 0);
            __builtin_amdgcn_global_load_lds(
                GLOBAL_AS(Bg + (size_t)(col0 + ar + lrow) * K + k0 + lc8),
                LDS_AS(&Bh[ar * BK]), 16, 0, 0);
        }
        __syncthreads();

        half8 af[4], bfr[4];
#pragma unroll
        for (int t = 0; t < 4; ++t) {
            af[t]  = *(const half8*)&Ah[(wr * 64 + t * 16 + l16) * BK + quad * 8];
            bfr[t] = *(const half8*)&Bh[(wc * 64 + t * 16 + l16) * BK + quad * 8];
        }
#pragma unroll
        for (int i = 0; i < 4; ++i)
#pragma unroll
            for (int j = 0; j < 4; ++j)
                acc[i][j] = __builtin_amdgcn_mfma_f32_16x16x32_f16(af[i], bfr[j], acc[i][j], 0, 0, 0);
    }

#pragma unroll
    for (int i = 0; i < 4; ++i) {
#pragma unroll
        for (int j = 0; j < 4; ++j) {
            const int colb = col0 + wc * 64 + j * 16 + l16;
            const float bv = bias[colb];
            const int rowb = row0 + wr * 64 + i * 16 + quad * 4;
            if (colb < 2048) {
                const float sc = (colb >= 1024) ? LOG2E : 1.0f;
#pragma unroll
                for (int r = 0; r < 4; ++r)
                    qk[(size_t)(rowb + r) * 2048 + colb] =
                        (_Float16)((acc[i][j][r] + bv) * sc);
            } else {
                half4 w;
#pragma unroll
                for (int r = 0; r < 4; ++r) w[r] = (_Float16)(acc[i][j][r] + bv);
                *(half4*)&vt[(size_t)(colb - 2048) * 4096 + rowb] = w;
            }
        }
    }
}

// ---------------------------------------------------------------------------
// Out-projection GEMM, fp16, 128(M)x64(N) tile -> 512 blocks (2/CU; was 256
// = 1/CU latency-bound). 4 waves: wave owns 32 M-rows x full 64 N.
// ---------------------------------------------------------------------------
__global__ __launch_bounds__(256) void gemm_out(
    const _Float16* __restrict__ Ag, const _Float16* __restrict__ Bg,
    const float* __restrict__ bias, float* __restrict__ C, int N, int K)
{
    constexpr int BK = 32;
    __shared__ _Float16 Ah[128 * BK];
    __shared__ _Float16 Bh[64 * BK];

    const int tid = threadIdx.x;
    const int wave = tid >> 6, lane = tid & 63;
    const int l16 = lane & 15, quad = lane >> 4;
    const int row0 = blockIdx.y * 128, col0 = blockIdx.x * 64;
    const int lrow = lane >> 2, lc8 = (lane & 3) * 8;

    float4_t acc[2][4];
#pragma unroll
    for (int i = 0; i < 2; ++i)
#pragma unroll
        for (int j = 0; j < 4; ++j) acc[i][j] = (float4_t){0.f, 0.f, 0.f, 0.f};

    for (int k0 = 0; k0 < K; k0 += BK) {
        __syncthreads();
#pragma unroll
        for (int i = 0; i < 2; ++i) {
            const int ar = i * 64 + wave * 16;
            __builtin_amdgcn_global_load_lds(
                GLOBAL_AS(Ag + (size_t)(row0 + ar + lrow) * K + k0 + lc8),
                LDS_AS(&Ah[ar * BK]), 16, 0, 0);
        }
        {
            const int br = wave * 16;
            __builtin_amdgcn_global_load_lds(
                GLOBAL_AS(Bg + (size_t)(col0 + br + lrow) * K + k0 + lc8),
                LDS_AS(&Bh[br * BK]), 16, 0, 0);
        }
        __syncthreads();

        half8 af[2], bfr[4];
#pragma unroll
        for (int t = 0; t < 2; ++t)
            af[t] = *(const half8*)&Ah[(wave * 32 + t * 16 + l16) * BK + quad * 8];
#pragma unroll
        for (int t = 0; t < 4; ++t)
            bfr[t] = *(const half8*)&Bh[(t * 16 + l16) * BK + quad * 8];
#pragma unroll
        for (int i = 0; i < 2; ++i)
#pragma unroll
            for (int j = 0; j < 4; ++j)
                acc[i][j] = __builtin_amdgcn_mfma_f32_16x16x32_f16(af[i], bfr[j], acc[i][j], 0, 0, 0);
    }

#pragma unroll
    for (int i = 0; i < 2; ++i) {
#pragma unroll
        for (int j = 0; j < 4; ++j) {
            const int colb = col0 + j * 16 + l16;
            const float bv = bias[colb];
#pragma unroll
            for (int r = 0; r < 4; ++r) {
                const int row = row0 + wave * 32 + i * 16 + quad * 4 + r;
                C[(size_t)row * N + colb] = acc[i][j][r] + bv;
            }
        }
    }
}

// ---------------------------------------------------------------------------
// MFMA causal flash attention — 32x32 MFMA RESTRUCTURE (this round).
// Rounds 0-4 post-mortem: pinned at ~90-100us; per-block-iter serial chain
// ~1650cy vs ~550cy issue work; TLP knobs exhausted. This round shrinks the
// chain itself by porting the guide's verified 32x32 structure:
//  - QK^T and PV use mfma_f32_32x32x16_f16; wave owns QBLK=32 q-rows.
//    4 waves x 32 = 128-row q-tile, 512 blocks x 256 threads.
//  - S^T = K Q^T: lane holds ALL 32 keys of one q-row (col=lane&31,
//    row=(reg&3)+8*(reg>>2)+4*(lane>>5)) -> softmax = 31 fmax + ONE
//    shfl_xor(32); P->PV B-operand built IN-REGISTER with 16 cvt_pkrtz +
//    8 permlane32_swap (VALU pipe, zero DS): swap(w0,w2).{a,b} etc. yields
//    fragment words directly for both lane halves. The Pb LDS round-trip
//    (~300cy: ds_write+lgkm+ds_read) leaves the critical path; round-3's
//    ds_bpermute bank-conflict failure cannot recur.
//  - LDS fragment reads per q-row HALVE (32 q share each K/V frag read);
//    LDS = 32 KB (no Pb).
//  - Tile schedule: s=bid>>4; tile = s<16 ? 31-s : s-16 -> each CU's two
//    blocks pair (31-s, s): uniform 68 iters/CU (old LPT was 96-vs-36).
//  - T5: s_setprio(1) around MFMA clusters (guide: +4-7% on attn).
// Kept: 64x64 K/V tiles DMA-staged (global_load_lds) into double-buffered
// XOR-swizzled LDS (source-permuted, dest linear): slot(row,col8) =
// row*8 + (col8 ^ (row&7)); ONE __syncthreads per k-iter; log2-domain
// logits (k plane pre-scaled by log2e); defer-max (T13); epilogue-deferred
// l-reduction; waves 0,1 skip the fully-masked trailing k-tile.
// ---------------------------------------------------------------------------
__global__ __launch_bounds__(256, 2) void flash_attn_f16(
    const _Float16* __restrict__ qk, const _Float16* __restrict__ v_t,
    _Float16* __restrict__ resh)
{
    __shared__ __align__(16) _Float16 KsT[2][64 * 64];   // [buf][slot*8]
    __shared__ __align__(16) _Float16 VtT[2][64 * 64];

    const int bid  = blockIdx.x;
    const int h    = (bid & 7) * 2 + ((bid >> 3) & 1);
    const int s_   = bid >> 4;                  // 0..31
    const int tile = (s_ < 16) ? (31 - s_) : (s_ - 16);  // CU pairs sum 31
    const int wave = threadIdx.x >> 6;          // 0..3
    const int lane = threadIdx.x & 63;
    const int l31  = lane & 31;
    const int hi   = lane >> 5;                 // 0/1

    // DMA source-address components (lane's LDS slot is wave*128+p*64+lane):
    const int dma_r = wave * 16 + (lane >> 3);             // row  (+ p*8)
    const int dma_c = ((lane & 7) ^ (lane >> 3)) * 8;      // logical col (halfs)

    const _Float16* kplane = qk + 1024 + h * HDIM;
    const _Float16* vplane = v_t + (size_t)h * HDIM * 4096;

    const int q0      = tile * 128 + wave * 32;
    const int kb_last = tile * 128 + 64;        // last 64-key tile start

    // ---- Q fragment (B-operand of 32x32x16): col=q=l31, k=16j+8*hi ------
    half8 qf[4];
#pragma unroll
    for (int j = 0; j < 4; ++j)
        qf[j] = *(const half8*)(qk + (size_t)(q0 + l31) * 2048 + h * HDIM
                                + j * 16 + hi * 8);

    float16_t o0 = (float16_t)0.f, o1 = (float16_t)0.f;
    float m_r = -INFINITY, l_r = 0.f;

    // ---- pre-stage tile kb=0 into buf 0 (LDS untouched before this) -------
#pragma unroll
    for (int p = 0; p < 2; ++p) {
        const int r = dma_r + p * 8;
        __builtin_amdgcn_global_load_lds(
            GLOBAL_AS(kplane + (size_t)r * 2048 + dma_c),
            LDS_AS(&KsT[0][(wave * 128 + p * 64) * 8]), 16, 0, 0);
        __builtin_amdgcn_global_load_lds(
            GLOBAL_AS(vplane + (size_t)r * 4096 + dma_c),
            LDS_AS(&VtT[0][(wave * 128 + p * 64) * 8]), 16, 0, 0);
    }

    int ib = 0;
    for (int kb = 0; kb <= kb_last; kb += 64, ib ^= 1) {
        __syncthreads();   // DMA(buf ib) done (vmcnt drain) + readers done

        if (kb < kb_last) {   // async DMA of next tile into the other buf
            const int kn = kb + 64;
#pragma unroll
            for (int p = 0; p < 2; ++p) {
                const int r = dma_r + p * 8;
                __builtin_amdgcn_global_load_lds(
                    GLOBAL_AS(kplane + (size_t)(kn + r) * 2048 + dma_c),
                    LDS_AS(&KsT[ib ^ 1][(wave * 128 + p * 64) * 8]), 16, 0, 0);
                __builtin_amdgcn_global_load_lds(
                    GLOBAL_AS(vplane + (size_t)r * 4096 + kn + dma_c),
                    LDS_AS(&VtT[ib ^ 1][(wave * 128 + p * 64) * 8]), 16, 0, 0);
            }
        }

        // waves 0,1: the final k-tile is entirely above the diagonal
        if (kb <= q0 + 31) {
            // ---- S^T = K Q^T (log2-domain logits), 2 key-chunks ----------
            float16_t s0 = (float16_t)0.f, s1 = (float16_t)0.f;
            __builtin_amdgcn_s_setprio(1);
#pragma unroll
            for (int j = 0; j < 4; ++j) {
                const int r7 = l31 & 7;
                const half8 kf0 = *(const half8*)&KsT[ib][
                    ((l31) * 8 + ((2 * j + hi) ^ r7)) * 8];
                const half8 kf1 = *(const half8*)&KsT[ib][
                    ((32 + l31) * 8 + ((2 * j + hi) ^ r7)) * 8];
                s0 = __builtin_amdgcn_mfma_f32_32x32x16_f16(kf0, qf[j], s0, 0, 0, 0);
                s1 = __builtin_amdgcn_mfma_f32_32x32x16_f16(kf1, qf[j], s1, 0, 0, 0);
            }
            __builtin_amdgcn_s_setprio(0);

            // ---- causal mask (diagonal-straddling tile only) --------------
            if (kb + 63 > q0) {
                const int qg = q0 + l31;
#pragma unroll
                for (int g = 0; g < 4; ++g)
#pragma unroll
                    for (int r = 0; r < 4; ++r) {
                        const int keyb = kb + r + 8 * g + 4 * hi;
                        if (keyb > qg)      s0[4 * g + r] = -INFINITY;
                        if (keyb + 32 > qg) s1[4 * g + r] = -INFINITY;
                    }
            }

            // ---- online softmax: 31 fmax + ONE shfl, defer-max (T13) ------
            float mx = s0[0];
#pragma unroll
            for (int i = 1; i < 16; ++i) mx = fmaxf(mx, s0[i]);
#pragma unroll
            for (int i = 0; i < 16; ++i) mx = fmaxf(mx, s1[i]);
            mx = fmaxf(mx, __shfl_xor(mx, 32));
            const bool  grow  = mx > m_r + 8.0f;
            const float mnew  = grow ? mx : m_r;
            const float alpha = __builtin_amdgcn_exp2f(m_r - mnew);  // ==1 if !grow

            // ---- P = exp2(S - m), pack to fp16 words ----------------------
            int w0[8], w1[8];
            float lsum = 0.f;
#pragma unroll
            for (int i = 0; i < 8; ++i) {
                const float pa = __builtin_amdgcn_exp2f(s0[2 * i]     - mnew);
                const float pb = __builtin_amdgcn_exp2f(s0[2 * i + 1] - mnew);
                lsum += pa + pb;
                w0[i] = __builtin_bit_cast(int, __builtin_amdgcn_cvt_pkrtz(pa, pb));
            }
#pragma unroll
            for (int i = 0; i < 8; ++i) {
                const float pa = __builtin_amdgcn_exp2f(s1[2 * i]     - mnew);
                const float pb = __builtin_amdgcn_exp2f(s1[2 * i + 1] - mnew);
                lsum += pa + pb;
                w1[i] = __builtin_bit_cast(int, __builtin_amdgcn_cvt_pkrtz(pa, pb));
            }
            l_r = l_r * alpha + lsum;   // per-lane partial (alpha row-uniform)
            m_r = mnew;
            if (__any(grow)) {
#pragma unroll
                for (int i = 0; i < 16; ++i) { o0[i] *= alpha; o1[i] *= alpha; }
            }

            // ---- P -> B-operand frags via permlane32_swap (no LDS) --------
            // frag[kc]: keys kc*16..+15; word m holds k-pair (8*hi+2m, +1).
            half8 pf[4];
            {
                const int2_t a02 = __builtin_amdgcn_permlane32_swap(w0[0], w0[2], 0, 0);
                const int2_t a13 = __builtin_amdgcn_permlane32_swap(w0[1], w0[3], 0, 0);
                const int2_t a46 = __builtin_amdgcn_permlane32_swap(w0[4], w0[6], 0, 0);
                const int2_t a57 = __builtin_amdgcn_permlane32_swap(w0[5], w0[7], 0, 0);
                int4_t f0 = {a02[0], a13[0], a02[1], a13[1]};
                int4_t f1 = {a46[0], a57[0], a46[1], a57[1]};
                pf[0] = __builtin_bit_cast(half8, f0);
                pf[1] = __builtin_bit_cast(half8, f1);
                const int2_t b02 = __builtin_amdgcn_permlane32_swap(w1[0], w1[2], 0, 0);
                const int2_t b13 = __builtin_amdgcn_permlane32_swap(w1[1], w1[3], 0, 0);
                const int2_t b46 = __builtin_amdgcn_permlane32_swap(w1[4], w1[6], 0, 0);
                const int2_t b57 = __builtin_amdgcn_permlane32_swap(w1[5], w1[7], 0, 0);
                int4_t f2 = {b02[0], b13[0], b02[1], b13[1]};
                int4_t f3 = {b46[0], b57[0], b46[1], b57[1]};
                pf[2] = __builtin_bit_cast(half8, f2);
                pf[3] = __builtin_bit_cast(half8, f3);
            }

            // ---- O^T += V^T P^T -------------------------------------------
            __builtin_amdgcn_s_setprio(1);
#pragma unroll
            for (int kc = 0; kc < 4; ++kc) {
                const int r7 = l31 & 7;
                const half8 vf0 = *(const half8*)&VtT[ib][
                    ((l31) * 8 + ((2 * kc + hi) ^ r7)) * 8];
                const half8 vf1 = *(const half8*)&VtT[ib][
                    ((32 + l31) * 8 + ((2 * kc + hi) ^ r7)) * 8];
                o0 = __builtin_amdgcn_mfma_f32_32x32x16_f16(vf0, pf[kc], o0, 0, 0, 0);
                o1 = __builtin_amdgcn_mfma_f32_32x32x16_f16(vf1, pf[kc], o1, 0, 0, 0);
            }
            __builtin_amdgcn_s_setprio(0);
        } // active
    } // kb

    // ---- epilogue: reduce l across halves, O^T[d][q]/l -> resh[q][d] ------
    float lr = l_r + __shfl_xor(l_r, 32);
    const float inv = 1.0f / lr;
#pragma unroll
    for (int g = 0; g < 4; ++g) {
        half4 wa, wb;
#pragma unroll
        for (int r = 0; r < 4; ++r) {
            wa[r] = (_Float16)(o0[4 * g + r] * inv);
            wb[r] = (_Float16)(o1[4 * g + r] * inv);
        }
        const size_t base = (size_t)(q0 + l31) * EMB + h * HDIM + 8 * g + 4 * hi;
        *(half4*)&resh[base]      = wa;
        *(half4*)&resh[base + 32] = wb;
    }
}

// ---------------------------------------------------------------------------
// launch
// ---------------------------------------------------------------------------
extern "C" void kernel_launch(void* const* d_in, const int* in_sizes, int n_in,
                              void* d_out, int out_size, void* d_ws, size_t ws_size,
                              hipStream_t stream)
{
    const float* x    = (const float*)d_in[0];
    const float* Wqkv = (const float*)d_in[2];
    const float* bqkv = (const float*)d_in[3];
    const float* Wp   = (const float*)d_in[4];
    const float* bp   = (const float*)d_in[5];
    float* out = (float*)d_out;

    _Float16* xh  = (_Float16*)d_ws;                 // [4096,1024] fp16
    _Float16* WTh = xh + (size_t)4096 * 1024;        // [3072,1024] fp16
    _Float16* qkh = WTh + (size_t)3072 * 1024;       // [4096,2048] fp16
    _Float16* vtg = qkh + (size_t)4096 * 2048;       // V^T [1024,4096] fp16
    _Float16* WpT = vtg + (size_t)1024 * 4096;       // [1024,1024] fp16
    _Float16* resh = xh;            // alias: x fp16 dead after QKV GEMM

    dim3 blk(256);

    prep<<<dim3(5120), blk, 0, stream>>>(x, Wqkv, Wp, xh, WTh, WpT);

    gemm_qkv<<<dim3(3072 / 128, 4096 / 128), blk, 0, stream>>>(
        xh, WTh, bqkv, qkh, vtg, 1024);

    flash_attn_f16<<<dim3(512), dim3(256), 0, stream>>>(qkh, vtg, resh);

    gemm_out<<<dim3(1024 / 64, 4096 / 128), blk, 0, stream>>>(
        resh, WpT, bp, out, 1024, 1024);
}

// Round 6
// 245.603 us; speedup vs baseline: 1.1002x; 1.0740x over previous
//
#include <hip/hip_runtime.h>
#include <hip/hip_bf16.h>
#include <math.h>

#define S_LEN 4096
#define EMB   1024
#define NHEAD 16
#define HDIM  64

typedef __attribute__((ext_vector_type(8))) _Float16 half8;
typedef __attribute__((ext_vector_type(4))) _Float16 half4;
typedef __attribute__((ext_vector_type(4))) float float4_t;
typedef __attribute__((ext_vector_type(16))) float float16_t;
typedef __attribute__((ext_vector_type(4))) int int4_t;
typedef __attribute__((ext_vector_type(2))) int int2_t;

#define GLOBAL_AS(p) ((const __attribute__((address_space(1))) void*)(p))
#define LDS_AS(p)    ((__attribute__((address_space(3))) void*)(p))

#define LOG2E 1.4426950408889634f

// ---------------------------------------------------------------------------
// fused prep: blocks [0,4096) convert x fp32->fp16; [4096,4864) transpose
// Wqkv [1024,3072] -> WTh [3072,1024]; [4864,5120) transpose Wp -> WpT.
// ---------------------------------------------------------------------------
__global__ __launch_bounds__(256) void prep(
    const float* __restrict__ x, const float* __restrict__ Wqkv,
    const float* __restrict__ Wp,
    _Float16* __restrict__ xh, _Float16* __restrict__ WTh,
    _Float16* __restrict__ WpT)
{
    const int bid = blockIdx.x;
    if (bid < 4096) {
        const int i = bid * 256 + threadIdx.x;
        const float4_t v = ((const float4_t*)x)[i];
        half4 hh;
#pragma unroll
        for (int j = 0; j < 4; ++j) hh[j] = (_Float16)v[j];
        ((half4*)xh)[i] = hh;
        return;
    }
    __shared__ float t[64][65];
    const float* in;
    _Float16* out;
    int R, C, bx, by;
    if (bid < 4096 + 768) {
        const int idx = bid - 4096;
        bx = idx % 48; by = idx / 48;
        in = Wqkv; out = WTh; R = 1024; C = 3072;
    } else {
        const int idx = bid - 4864;
        bx = idx & 15; by = idx >> 4;
        in = Wp; out = WpT; R = 1024; C = 1024;
    }
    const int r0 = by * 64, c0 = bx * 64;
    for (int i = threadIdx.x; i < 64 * 64; i += 256) {
        int r = i >> 6, c = i & 63;
        t[r][c] = in[(size_t)(r0 + r) * C + c0 + c];
    }
    __syncthreads();
    for (int i = threadIdx.x; i < 64 * 64; i += 256) {
        int c = i >> 6, r = i & 63;
        out[(size_t)(c0 + c) * R + r0 + r] = (_Float16)t[r][c];
    }
}

// ---------------------------------------------------------------------------
// QKV GEMM, plain fp16, m97 structure: 128x128 tile, BK=32, global_load_lds.
// Epilogue: cols<1024 -> q plane; 1024..2047 -> k plane SCALED by log2(e);
// cols>=2048 -> fp16 V^T [1024,4096], packed half4 along s.
// ---------------------------------------------------------------------------
__global__ __launch_bounds__(256) void gemm_qkv(
    const _Float16* __restrict__ Ag, const _Float16* __restrict__ Bg,
    const float* __restrict__ bias,
    _Float16* __restrict__ qk, _Float16* __restrict__ vt, int K)
{
    constexpr int BK = 32;
    __shared__ _Float16 Ah[128 * BK];
    __shared__ _Float16 Bh[128 * BK];

    const int tid = threadIdx.x;
    const int wave = tid >> 6, lane = tid & 63;
    const int l16 = lane & 15, quad = lane >> 4;
    const int wr = wave >> 1, wc = wave & 1;
    const int row0 = blockIdx.y * 128, col0 = blockIdx.x * 128;
    const int lrow = lane >> 2, lc8 = (lane & 3) * 8;

    float4_t acc[4][4];
#pragma unroll
    for (int i = 0; i < 4; ++i)
#pragma unroll
        for (int j = 0; j < 4; ++j) acc[i][j] = (float4_t){0.f, 0.f, 0.f, 0.f};

    for (int k0 = 0; k0 < K; k0 += BK) {
        __syncthreads();
#pragma unroll
        for (int i = 0; i < 2; ++i) {
            const int ar = i * 64 + wave * 16;
            __builtin_amdgcn_global_load_lds(
                GLOBAL_AS(Ag + (size_t)(row0 + ar + lrow) * K + k0 + lc8),
                LDS_AS(&Ah[ar * BK]), 16, 0, 0);
            __builtin_amdgcn_global_load_lds(
                GLOBAL_AS(Bg + (size_t)(col0 + ar + lrow) * K + k0 + lc8),
                LDS_AS(&Bh[ar * BK]), 16, 0, 0);
        }
        __syncthreads();

        half8 af[4], bfr[4];
#pragma unroll
        for (int t = 0; t < 4; ++t) {
            af[t]  = *(const half8*)&Ah[(wr * 64 + t * 16 + l16) * BK + quad * 8];
            bfr[t] = *(const half8*)&Bh[(wc * 64 + t * 16 + l16) * BK + quad * 8];
        }
#pragma unroll
        for (int i = 0; i < 4; ++i)
#pragma unroll
            for (int j = 0; j < 4; ++j)
                acc[i][j] = __builtin_amdgcn_mfma_f32_16x16x32_f16(af[i], bfr[j], acc[i][j], 0, 0, 0);
    }

#pragma unroll
    for (int i = 0; i < 4; ++i) {
#pragma unroll
        for (int j = 0; j < 4; ++j) {
            const int colb = col0 + wc * 64 + j * 16 + l16;
            const float bv = bias[colb];
            const int rowb = row0 + wr * 64 + i * 16 + quad * 4;
            if (colb < 2048) {
                const float sc = (colb >= 1024) ? LOG2E : 1.0f;
#pragma unroll
                for (int r = 0; r < 4; ++r)
                    qk[(size_t)(rowb + r) * 2048 + colb] =
                        (_Float16)((acc[i][j][r] + bv) * sc);
            } else {
                half4 w;
#pragma unroll
                for (int r = 0; r < 4; ++r) w[r] = (_Float16)(acc[i][j][r] + bv);
                *(half4*)&vt[(size_t)(colb - 2048) * 4096 + rowb] = w;
            }
        }
    }
}

// ---------------------------------------------------------------------------
// Out-projection GEMM, fp16, 128(M)x64(N) tile -> 512 blocks (2/CU; was 256
// = 1/CU latency-bound). 4 waves: wave owns 32 M-rows x full 64 N.
// ---------------------------------------------------------------------------
__global__ __launch_bounds__(256) void gemm_out(
    const _Float16* __restrict__ Ag, const _Float16* __restrict__ Bg,
    const float* __restrict__ bias, float* __restrict__ C, int N, int K)
{
    constexpr int BK = 32;
    __shared__ _Float16 Ah[128 * BK];
    __shared__ _Float16 Bh[64 * BK];

    const int tid = threadIdx.x;
    const int wave = tid >> 6, lane = tid & 63;
    const int l16 = lane & 15, quad = lane >> 4;
    const int row0 = blockIdx.y * 128, col0 = blockIdx.x * 64;
    const int lrow = lane >> 2, lc8 = (lane & 3) * 8;

    float4_t acc[2][4];
#pragma unroll
    for (int i = 0; i < 2; ++i)
#pragma unroll
        for (int j = 0; j < 4; ++j) acc[i][j] = (float4_t){0.f, 0.f, 0.f, 0.f};

    for (int k0 = 0; k0 < K; k0 += BK) {
        __syncthreads();
#pragma unroll
        for (int i = 0; i < 2; ++i) {
            const int ar = i * 64 + wave * 16;
            __builtin_amdgcn_global_load_lds(
                GLOBAL_AS(Ag + (size_t)(row0 + ar + lrow) * K + k0 + lc8),
                LDS_AS(&Ah[ar * BK]), 16, 0, 0);
        }
        {
            const int br = wave * 16;
            __builtin_amdgcn_global_load_lds(
                GLOBAL_AS(Bg + (size_t)(col0 + br + lrow) * K + k0 + lc8),
                LDS_AS(&Bh[br * BK]), 16, 0, 0);
        }
        __syncthreads();

        half8 af[2], bfr[4];
#pragma unroll
        for (int t = 0; t < 2; ++t)
            af[t] = *(const half8*)&Ah[(wave * 32 + t * 16 + l16) * BK + quad * 8];
#pragma unroll
        for (int t = 0; t < 4; ++t)
            bfr[t] = *(const half8*)&Bh[(t * 16 + l16) * BK + quad * 8];
#pragma unroll
        for (int i = 0; i < 2; ++i)
#pragma unroll
            for (int j = 0; j < 4; ++j)
                acc[i][j] = __builtin_amdgcn_mfma_f32_16x16x32_f16(af[i], bfr[j], acc[i][j], 0, 0, 0);
    }

#pragma unroll
    for (int i = 0; i < 2; ++i) {
#pragma unroll
        for (int j = 0; j < 4; ++j) {
            const int colb = col0 + j * 16 + l16;
            const float bv = bias[colb];
#pragma unroll
            for (int r = 0; r < 4; ++r) {
                const int row = row0 + wave * 32 + i * 16 + quad * 4 + r;
                C[(size_t)row * N + colb] = acc[i][j][r] + bv;
            }
        }
    }
}

// ---------------------------------------------------------------------------
// MFMA causal flash attention — 2-WAY SPLIT-K round.
// Round-5 post-mortem: 32x32 structure helped (chain shrank: VALUBusy 47->31)
// but occupancy collapsed to 12% — concurrent (heavy,light) pairing decayed
// to 1 wave/SIMD for the heavy tail, and the chain (~3.2kcy/iter vs ~1kcy
// issue) needs TLP. This round: keep the round-5 per-wave inner loop
// IDENTICAL, but split each (head, 128-row tile) across TWO blocks:
// split 0 = even 64-key tiles, split 1 = odd (exactly t+1 iters each).
//  - grid 1024 x 256thr: 4 blocks/CU x 4 waves = 16 waves/CU (4/SIMD);
//    LDS 32KB x4 = 128KB, VGPR ~70 <= 128. 2x round-5 peak TLP, sustained.
//  - per-CU balance BY CONSTRUCTION: CU g hosts {(j,s0),(31-j,s0),(j,s1),
//    (31-j,s1)} -> iters sum = 66 for every CU.
//  - blocks store UNNORMALIZED partial O (fp16) + (m,l) (f32); combine
//    kernel merges: m=max, l=l0*2^(m0-m)+l1*2^(m1-m), O likewise, /l.
//    defer-max partials are self-consistent w.r.t. their own m -> exact.
//    Empty waves (t=0,s1,w<2) store m=-inf,l=0 -> weight exp2(-inf)=0;
//    split 0 always covers kb=0 so l0>0 (no div-by-0).
// Kept: 64x64 K/V tiles DMA-staged into double-buffered XOR-swizzled LDS
// (slot(row,col8)=row*8+(col8^(row&7))), ONE __syncthreads per k-iter,
// S^T=K Q^T log2-domain, 31-fmax+1-shfl softmax, cvt_pkrtz+permlane32_swap
// P-exchange (pure VALU), defer-max (T13), setprio (T5).
// ---------------------------------------------------------------------------
__global__ __launch_bounds__(256, 4) void flash_attn_f16(
    const _Float16* __restrict__ qk, const _Float16* __restrict__ v_t,
    _Float16* __restrict__ opart, float* __restrict__ mlpart)
{
    __shared__ __align__(16) _Float16 KsT[2][64 * 64];   // [buf][slot*8]
    __shared__ __align__(16) _Float16 VtT[2][64 * 64];

    const int bid  = blockIdx.x;
    const int g    = bid & 255;                 // residency group (CU)
    const int hv   = g & 15;
    const int h    = (hv & 7) * 2 + (hv >> 3);  // XCD-pinned heads
    const int j    = g >> 4;                    // 0..15
    const int v    = bid >> 8;                  // 0..3
    const int tile = (v & 1) ? (31 - j) : j;    // quartet sums to 66 iters
    const int split= v >> 1;                    // 0: even k-tiles, 1: odd

    const int wave = threadIdx.x >> 6;          // 0..3
    const int lane = threadIdx.x & 63;
    const int l31  = lane & 31;
    const int hi   = lane >> 5;                 // 0/1

    // DMA source-address components (lane's LDS slot is wave*128+p*64+lane):
    const int dma_r = wave * 16 + (lane >> 3);             // row  (+ p*8)
    const int dma_c = ((lane & 7) ^ (lane >> 3)) * 8;      // logical col (halfs)

    const _Float16* kplane = qk + 1024 + h * HDIM;
    const _Float16* vplane = v_t + (size_t)h * HDIM * 4096;

    const int q0 = tile * 128 + wave * 32;

    // ---- Q fragment (B-operand of 32x32x16): col=q=l31, k=16j+8*hi ------
    half8 qf[4];
#pragma unroll
    for (int jj = 0; jj < 4; ++jj)
        qf[jj] = *(const half8*)(qk + (size_t)(q0 + l31) * 2048 + h * HDIM
                                 + jj * 16 + hi * 8);

    float16_t o0 = (float16_t)0.f, o1 = (float16_t)0.f;
    float m_r = -INFINITY, l_r = 0.f;

    // ---- pre-stage first k-tile (kb = 64*split) into buf 0 ----------------
    const int kb0 = 64 * split;
#pragma unroll
    for (int p = 0; p < 2; ++p) {
        const int r = dma_r + p * 8;
        __builtin_amdgcn_global_load_lds(
            GLOBAL_AS(kplane + (size_t)(kb0 + r) * 2048 + dma_c),
            LDS_AS(&KsT[0][(wave * 128 + p * 64) * 8]), 16, 0, 0);
        __builtin_amdgcn_global_load_lds(
            GLOBAL_AS(vplane + (size_t)r * 4096 + kb0 + dma_c),
            LDS_AS(&VtT[0][(wave * 128 + p * 64) * 8]), 16, 0, 0);
    }

    int ib = 0;
    int kb = kb0;
    for (int it = 0; it <= tile; ++it, kb += 128, ib ^= 1) {
        __syncthreads();   // DMA(buf ib) done (vmcnt drain) + readers done

        if (it < tile) {   // async DMA of next tile (stride 128) into buf^1
            const int kn = kb + 128;
#pragma unroll
            for (int p = 0; p < 2; ++p) {
                const int r = dma_r + p * 8;
                __builtin_amdgcn_global_load_lds(
                    GLOBAL_AS(kplane + (size_t)(kn + r) * 2048 + dma_c),
                    LDS_AS(&KsT[ib ^ 1][(wave * 128 + p * 64) * 8]), 16, 0, 0);
                __builtin_amdgcn_global_load_lds(
                    GLOBAL_AS(vplane + (size_t)r * 4096 + kn + dma_c),
                    LDS_AS(&VtT[ib ^ 1][(wave * 128 + p * 64) * 8]), 16, 0, 0);
            }
        }

        // fully-masked trailing tile (split 1, waves 0/1): skip compute
        if (kb <= q0 + 31) {
            // ---- S^T = K Q^T (log2-domain logits), 2 key-chunks ----------
            float16_t s0 = (float16_t)0.f, s1 = (float16_t)0.f;
            __builtin_amdgcn_s_setprio(1);
#pragma unroll
            for (int jj = 0; jj < 4; ++jj) {
                const int r7 = l31 & 7;
                const half8 kf0 = *(const half8*)&KsT[ib][
                    ((l31) * 8 + ((2 * jj + hi) ^ r7)) * 8];
                const half8 kf1 = *(const half8*)&KsT[ib][
                    ((32 + l31) * 8 + ((2 * jj + hi) ^ r7)) * 8];
                s0 = __builtin_amdgcn_mfma_f32_32x32x16_f16(kf0, qf[jj], s0, 0, 0, 0);
                s1 = __builtin_amdgcn_mfma_f32_32x32x16_f16(kf1, qf[jj], s1, 0, 0, 0);
            }
            __builtin_amdgcn_s_setprio(0);

            // ---- causal mask (diagonal-straddling tile only) --------------
            if (kb + 63 > q0) {
                const int qg = q0 + l31;
#pragma unroll
                for (int gg = 0; gg < 4; ++gg)
#pragma unroll
                    for (int r = 0; r < 4; ++r) {
                        const int keyb = kb + r + 8 * gg + 4 * hi;
                        if (keyb > qg)      s0[4 * gg + r] = -INFINITY;
                        if (keyb + 32 > qg) s1[4 * gg + r] = -INFINITY;
                    }
            }

            // ---- online softmax: 31 fmax + ONE shfl, defer-max (T13) ------
            float mx = s0[0];
#pragma unroll
            for (int i = 1; i < 16; ++i) mx = fmaxf(mx, s0[i]);
#pragma unroll
            for (int i = 0; i < 16; ++i) mx = fmaxf(mx, s1[i]);
            mx = fmaxf(mx, __shfl_xor(mx, 32));
            const bool  grow  = mx > m_r + 8.0f;
            const float mnew  = grow ? mx : m_r;
            const float alpha = __builtin_amdgcn_exp2f(m_r - mnew);  // ==1 if !grow

            // ---- P = exp2(S - m), pack to fp16 words ----------------------
            int w0[8], w1[8];
            float lsum = 0.f;
#pragma unroll
            for (int i = 0; i < 8; ++i) {
                const float pa = __builtin_amdgcn_exp2f(s0[2 * i]     - mnew);
                const float pb = __builtin_amdgcn_exp2f(s0[2 * i + 1] - mnew);
                lsum += pa + pb;
                w0[i] = __builtin_bit_cast(int, __builtin_amdgcn_cvt_pkrtz(pa, pb));
            }
#pragma unroll
            for (int i = 0; i < 8; ++i) {
                const float pa = __builtin_amdgcn_exp2f(s1[2 * i]     - mnew);
                const float pb = __builtin_amdgcn_exp2f(s1[2 * i + 1] - mnew);
                lsum += pa + pb;
                w1[i] = __builtin_bit_cast(int, __builtin_amdgcn_cvt_pkrtz(pa, pb));
            }
            l_r = l_r * alpha + lsum;   // per-lane partial (alpha row-uniform)
            m_r = mnew;
            if (__any(grow)) {
#pragma unroll
                for (int i = 0; i < 16; ++i) { o0[i] *= alpha; o1[i] *= alpha; }
            }

            // ---- P -> B-operand frags via permlane32_swap (no LDS) --------
            half8 pf[4];
            {
                const int2_t a02 = __builtin_amdgcn_permlane32_swap(w0[0], w0[2], 0, 0);
                const int2_t a13 = __builtin_amdgcn_permlane32_swap(w0[1], w0[3], 0, 0);
                const int2_t a46 = __builtin_amdgcn_permlane32_swap(w0[4], w0[6], 0, 0);
                const int2_t a57 = __builtin_amdgcn_permlane32_swap(w0[5], w0[7], 0, 0);
                int4_t f0 = {a02[0], a13[0], a02[1], a13[1]};
                int4_t f1 = {a46[0], a57[0], a46[1], a57[1]};
                pf[0] = __builtin_bit_cast(half8, f0);
                pf[1] = __builtin_bit_cast(half8, f1);
                const int2_t b02 = __builtin_amdgcn_permlane32_swap(w1[0], w1[2], 0, 0);
                const int2_t b13 = __builtin_amdgcn_permlane32_swap(w1[1], w1[3], 0, 0);
                const int2_t b46 = __builtin_amdgcn_permlane32_swap(w1[4], w1[6], 0, 0);
                const int2_t b57 = __builtin_amdgcn_permlane32_swap(w1[5], w1[7], 0, 0);
                int4_t f2 = {b02[0], b13[0], b02[1], b13[1]};
                int4_t f3 = {b46[0], b57[0], b46[1], b57[1]};
                pf[2] = __builtin_bit_cast(half8, f2);
                pf[3] = __builtin_bit_cast(half8, f3);
            }

            // ---- O^T += V^T P^T -------------------------------------------
            __builtin_amdgcn_s_setprio(1);
#pragma unroll
            for (int kc = 0; kc < 4; ++kc) {
                const int r7 = l31 & 7;
                const half8 vf0 = *(const half8*)&VtT[ib][
                    ((l31) * 8 + ((2 * kc + hi) ^ r7)) * 8];
                const half8 vf1 = *(const half8*)&VtT[ib][
                    ((32 + l31) * 8 + ((2 * kc + hi) ^ r7)) * 8];
                o0 = __builtin_amdgcn_mfma_f32_32x32x16_f16(vf0, pf[kc], o0, 0, 0, 0);
                o1 = __builtin_amdgcn_mfma_f32_32x32x16_f16(vf1, pf[kc], o1, 0, 0, 0);
            }
            __builtin_amdgcn_s_setprio(0);
        } // active
    } // kb

    // ---- epilogue: store UNNORMALIZED partials + (m, l) -------------------
    const float lr = l_r + __shfl_xor(l_r, 32);
    const size_t prow = (size_t)(split * 4096 + q0 + l31);
#pragma unroll
    for (int gg = 0; gg < 4; ++gg) {
        half4 wa, wb;
#pragma unroll
        for (int r = 0; r < 4; ++r) {
            wa[r] = (_Float16)o0[4 * gg + r];
            wb[r] = (_Float16)o1[4 * gg + r];
        }
        const size_t base = prow * 1024 + h * HDIM + 8 * gg + 4 * hi;
        *(half4*)&opart[base]      = wa;
        *(half4*)&opart[base + 32] = wb;
    }
    if (hi == 0) {
        float2 ml; ml.x = m_r; ml.y = lr;
        ((float2*)mlpart)[prow * 16 + h] = ml;
    }
}

// ---------------------------------------------------------------------------
// combine: merge the two split-K partials per (row, head); write resh fp16.
// 524288 threads, one half8 of d-values each. ~25 MB traffic, ~6 us.
// ---------------------------------------------------------------------------
__global__ __launch_bounds__(256) void combine(
    const _Float16* __restrict__ opart, const float* __restrict__ mlpart,
    _Float16* __restrict__ resh)
{
    const int idx = blockIdx.x * 256 + threadIdx.x;   // 0..524287
    const int row = idx >> 7;                          // 0..4095
    const int c8  = (idx & 127) * 8;                   // d-offset in the row
    const int h   = c8 >> 6;
    const float2 ml0 = ((const float2*)mlpart)[(size_t)row * 16 + h];
    const float2 ml1 = ((const float2*)mlpart)[(size_t)(4096 + row) * 16 + h];
    const float m  = fmaxf(ml0.x, ml1.x);              // m0 always finite
    const float a0 = __builtin_amdgcn_exp2f(ml0.x - m);
    const float a1 = __builtin_amdgcn_exp2f(ml1.x - m);  // 0 if m1 = -inf
    const float inv = 1.0f / (ml0.y * a0 + ml1.y * a1);  // l0 > 0 always
    const half8 o0 = *(const half8*)&opart[(size_t)row * 1024 + c8];
    const half8 o1 = *(const half8*)&opart[(size_t)(4096 + row) * 1024 + c8];
    half8 w;
#pragma unroll
    for (int jj = 0; jj < 8; ++jj)
        w[jj] = (_Float16)(((float)o0[jj] * a0 + (float)o1[jj] * a1) * inv);
    *(half8*)&resh[(size_t)row * 1024 + c8] = w;
}

// ---------------------------------------------------------------------------
// launch
// ---------------------------------------------------------------------------
extern "C" void kernel_launch(void* const* d_in, const int* in_sizes, int n_in,
                              void* d_out, int out_size, void* d_ws, size_t ws_size,
                              hipStream_t stream)
{
    const float* x    = (const float*)d_in[0];
    const float* Wqkv = (const float*)d_in[2];
    const float* bqkv = (const float*)d_in[3];
    const float* Wp   = (const float*)d_in[4];
    const float* bp   = (const float*)d_in[5];
    float* out = (float*)d_out;

    _Float16* xh  = (_Float16*)d_ws;                 // [4096,1024] fp16  8MB
    _Float16* WTh = xh + (size_t)4096 * 1024;        // [3072,1024] fp16  6MB
    _Float16* qkh = WTh + (size_t)3072 * 1024;       // [4096,2048] fp16 16MB
    _Float16* vtg = qkh + (size_t)4096 * 2048;       // V^T [1024,4096]   8MB
    _Float16* WpT = vtg + (size_t)1024 * 4096;       // [1024,1024] fp16  2MB
    _Float16* opart = WpT + (size_t)1024 * 1024;     // [2,4096,1024] fp16 16MB
    float* mlpart = (float*)(opart + (size_t)2 * 4096 * 1024);  // [2,4096,16,2] f32 1MB
    _Float16* resh = xh;            // alias: x fp16 dead after QKV GEMM

    dim3 blk(256);

    prep<<<dim3(5120), blk, 0, stream>>>(x, Wqkv, Wp, xh, WTh, WpT);

    gemm_qkv<<<dim3(3072 / 128, 4096 / 128), blk, 0, stream>>>(
        xh, WTh, bqkv, qkh, vtg, 1024);

    flash_attn_f16<<<dim3(1024), dim3(256), 0, stream>>>(qkh, vtg, opart, mlpart);

    combine<<<dim3(2048), blk, 0, stream>>>(opart, mlpart, resh);

    gemm_out<<<dim3(1024 / 64, 4096 / 128), blk, 0, stream>>>(
        resh, WpT, bp, out, 1024, 1024);
}